// Round 1
// baseline (600.119 us; speedup 1.0000x reference)
//
#include <hip/hip_runtime.h>
#include <cstdint>

typedef _Float16 f16;
typedef f16 f16x8 __attribute__((ext_vector_type(8)));
typedef float f32x4 __attribute__((ext_vector_type(4)));

typedef __attribute__((address_space(1))) void gvoid_t;
typedef __attribute__((address_space(3))) void lvoid_t;

__device__ __forceinline__ void gload_lds16(const void* g, void* l) {
    // async global->LDS, 16B per lane; LDS dest is wave-uniform base + lane*16
    __builtin_amdgcn_global_load_lds((gvoid_t*)const_cast<void*>(g),
                                     (lvoid_t*)l, 16, 0, 0);
}

// C[m,n] = sum_k A[m,k] * B[n,k]   (A: [M,K] row-major, B: [N,K] row-major, f16)
// EPI 0: f16 out, + bias[row]   (projections q,k)
// EPI 1: f16 out, + bias[col]   (vT)
// EPI 2: f32 out, * scale       (S = qk^T / sqrt(C))
// EPI 3: f32 out                (final out)
template<int EPI>
__global__ __launch_bounds__(256) void gemm_nt(
    const f16* __restrict__ A, const f16* __restrict__ B,
    void* __restrict__ Cv, const float* __restrict__ bias,
    int M, int N, int K,
    long long sA, long long sB, long long sC, float scale)
{
    const int b = blockIdx.z;
    const f16* Ab = A + (long long)b * sA;
    const f16* Bb = B + (long long)b * sB;

    __shared__ alignas(16) f16 As[128 * 32];
    __shared__ alignas(16) f16 Bs[128 * 32];

    const int tid  = threadIdx.x;
    const int wave = tid >> 6;
    const int lane = tid & 63;
    const int quad = lane >> 4;
    const int l16  = lane & 15;

    const int m0 = blockIdx.x * 128;
    const int n0 = blockIdx.y * 128;
    const int wm = (wave >> 1) * 64;   // wave row offset in tile
    const int wn = (wave & 1) * 64;    // wave col offset in tile

    // staging: thread t loads 16B (8 f16): tile row t>>2, k-cols (t&3)*8..+7
    const int srow = tid >> 2;
    const int scol = (tid & 3) * 8;

    const f16* Ag = Ab + (long long)(m0 + srow) * K + scol;
    const f16* Bg = Bb + (long long)(n0 + srow) * K + scol;
    f16* Asl = &As[tid * 8];
    f16* Bsl = &Bs[tid * 8];
    const long long rowskip = 64LL * K;

    f32x4 acc[4][4] = {};

    for (int kk = 0; kk < K; kk += 32) {
        gload_lds16(Ag,            Asl);
        gload_lds16(Ag + rowskip,  Asl + 2048);
        gload_lds16(Bg,            Bsl);
        gload_lds16(Bg + rowskip,  Bsl + 2048);
        Ag += 32; Bg += 32;
        __syncthreads();   // drains vmcnt -> LDS tiles ready

        f16x8 af[4], bf[4];
        #pragma unroll
        for (int i = 0; i < 4; i++)
            af[i] = *reinterpret_cast<const f16x8*>(&As[(wm + i * 16 + l16) * 32 + quad * 8]);
        #pragma unroll
        for (int j = 0; j < 4; j++)
            bf[j] = *reinterpret_cast<const f16x8*>(&Bs[(wn + j * 16 + l16) * 32 + quad * 8]);
        #pragma unroll
        for (int i = 0; i < 4; i++)
            #pragma unroll
            for (int j = 0; j < 4; j++)
                acc[i][j] = __builtin_amdgcn_mfma_f32_16x16x32_f16(af[i], bf[j], acc[i][j], 0, 0, 0);
        __syncthreads();   // all waves done reading before next stage overwrites
    }

    // epilogue: C/D layout col=lane&15, row=quad*4+reg (verified m89/m91)
    #pragma unroll
    for (int i = 0; i < 4; i++) {
        #pragma unroll
        for (int j = 0; j < 4; j++) {
            #pragma unroll
            for (int r = 0; r < 4; r++) {
                const int row = m0 + wm + i * 16 + quad * 4 + r;
                const int col = n0 + wn + j * 16 + l16;
                const float v = acc[i][j][r];
                const long long idx = (long long)b * sC + (long long)row * N + col;
                if constexpr (EPI == 0) {
                    ((f16*)Cv)[idx] = (f16)(v + bias[row]);
                } else if constexpr (EPI == 1) {
                    ((f16*)Cv)[idx] = (f16)(v + bias[col]);
                } else if constexpr (EPI == 2) {
                    ((float*)Cv)[idx] = v * scale;
                } else {
                    ((float*)Cv)[idx] = v;
                }
            }
        }
    }
}

// x [B,512,4096] f32 -> xT [B,4096,512] f16
__global__ __launch_bounds__(256) void transpose_cast(
    const float* __restrict__ x, f16* __restrict__ xT)
{
    __shared__ float t[32][33];
    const int b  = blockIdx.z;
    const int n0 = blockIdx.x * 32;
    const int c0 = blockIdx.y * 32;
    const int tx = threadIdx.x & 31;
    const int ty = threadIdx.x >> 5;   // 0..7

    const float* xb = x + ((long long)b * 512 + c0) * 4096 + n0;
    #pragma unroll
    for (int i = 0; i < 32; i += 8)
        t[ty + i][tx] = xb[(long long)(ty + i) * 4096 + tx];
    __syncthreads();
    f16* xTb = xT + ((long long)b * 4096 + n0) * 512 + c0;
    #pragma unroll
    for (int i = 0; i < 32; i += 8)
        xTb[(long long)(ty + i) * 512 + tx] = (f16)t[tx][ty + i];
}

__global__ __launch_bounds__(256) void cast_w(
    const float* __restrict__ W, f16* __restrict__ o, int n)
{
    int i = blockIdx.x * 256 + threadIdx.x;
    if (i < n) o[i] = (f16)W[i];
}

// row softmax over S [8192 rows, 512 cols] f32 -> attn f16
__global__ __launch_bounds__(256) void softmax_rows(
    const float* __restrict__ S, f16* __restrict__ P)
{
    const int wave = threadIdx.x >> 6;
    const int lane = threadIdx.x & 63;
    const long long row = (long long)blockIdx.x * 4 + wave;
    const float* src = S + row * 512;

    float v[8];
    float mx = -1e30f;
    #pragma unroll
    for (int j = 0; j < 8; j++) { v[j] = src[lane + 64 * j]; mx = fmaxf(mx, v[j]); }
    #pragma unroll
    for (int off = 32; off > 0; off >>= 1) mx = fmaxf(mx, __shfl_xor(mx, off, 64));
    float sum = 0.f;
    #pragma unroll
    for (int j = 0; j < 8; j++) { v[j] = __expf(v[j] - mx); sum += v[j]; }
    #pragma unroll
    for (int off = 32; off > 0; off >>= 1) sum += __shfl_xor(sum, off, 64);
    const float inv = 1.0f / sum;
    f16* dst = P + row * 512;
    #pragma unroll
    for (int j = 0; j < 8; j++) dst[lane + 64 * j] = (f16)(v[j] * inv);
}

extern "C" void kernel_launch(void* const* d_in, const int* in_sizes, int n_in,
                              void* d_out, int out_size, void* d_ws, size_t ws_size,
                              hipStream_t stream)
{
    const float* x  = (const float*)d_in[0];
    const float* Wq = (const float*)d_in[1];
    const float* bq = (const float*)d_in[2];
    const float* Wk = (const float*)d_in[3];
    const float* bk = (const float*)d_in[4];
    const float* Wv = (const float*)d_in[5];
    const float* bv = (const float*)d_in[6];
    float* out = (float*)d_out;

    const int B = 16, C = 512, N = 4096;

    char* ws = (char*)d_ws;
    size_t off = 0;
    auto alloc = [&](size_t bytes) -> void* {
        void* p = ws + off;
        off += (bytes + 255) & ~(size_t)255;
        return p;
    };
    f16*   xT   = (f16*)  alloc((size_t)B * N * C * 2);   // 64 MiB
    f16*   q    = (f16*)  alloc((size_t)B * C * N * 2);   // 64 MiB
    f16*   k    = (f16*)  alloc((size_t)B * C * N * 2);   // 64 MiB
    f16*   vT   = (f16*)  alloc((size_t)B * N * C * 2);   // 64 MiB
    float* S    = (float*)alloc((size_t)B * C * C * 4);   // 16 MiB
    f16*   attn = (f16*)  alloc((size_t)B * C * C * 2);   //  8 MiB
    f16*   Wqh  = (f16*)  alloc((size_t)C * C * 2);
    f16*   Wkh  = (f16*)  alloc((size_t)C * C * 2);
    f16*   Wvh  = (f16*)  alloc((size_t)C * C * 2);
    (void)ws_size;

    transpose_cast<<<dim3(N / 32, C / 32, B), 256, 0, stream>>>(x, xT);
    cast_w<<<dim3(C * C / 256), 256, 0, stream>>>(Wq, Wqh, C * C);
    cast_w<<<dim3(C * C / 256), 256, 0, stream>>>(Wk, Wkh, C * C);
    cast_w<<<dim3(C * C / 256), 256, 0, stream>>>(Wv, Wvh, C * C);

    // q[b] = Wq * x[b]  -> [C, N] f16 (+bq over rows)
    gemm_nt<0><<<dim3(C / 128, N / 128, B), 256, 0, stream>>>(
        Wqh, xT, q, bq, C, N, C, 0LL, (long long)N * C, (long long)C * N, 1.0f);
    // k[b] = Wk * x[b]  -> [C, N] f16 (+bk over rows)
    gemm_nt<0><<<dim3(C / 128, N / 128, B), 256, 0, stream>>>(
        Wkh, xT, k, bk, C, N, C, 0LL, (long long)N * C, (long long)C * N, 1.0f);
    // vT[b] = (Wv * x[b])^T -> [N, C] f16 (+bv over cols)
    gemm_nt<1><<<dim3(N / 128, C / 128, B), 256, 0, stream>>>(
        xT, Wvh, vT, bv, N, C, C, (long long)N * C, 0LL, (long long)N * C, 1.0f);
    // S[b] = q[b] k[b]^T / sqrt(C) -> [C, C] f32
    gemm_nt<2><<<dim3(C / 128, C / 128, B), 256, 0, stream>>>(
        q, k, S, nullptr, C, C, N, (long long)C * N, (long long)C * N,
        (long long)C * C, 0.04419417382415922f);
    // attn = softmax rows
    softmax_rows<<<dim3(B * C / 4), 256, 0, stream>>>(S, attn);
    // out[b] = attn[b] * v[b] -> [C, N] f32
    gemm_nt<3><<<dim3(C / 128, N / 128, B), 256, 0, stream>>>(
        attn, vT, out, nullptr, C, N, C, (long long)C * C, (long long)N * C,
        (long long)C * N, 1.0f);
}

// Round 2
// 482.704 us; speedup vs baseline: 1.2432x; 1.2432x over previous
//
#include <hip/hip_runtime.h>
#include <cstdint>

typedef _Float16 f16;
typedef f16 f16x4 __attribute__((ext_vector_type(4)));
typedef f16 f16x8 __attribute__((ext_vector_type(8)));
typedef float f32x4 __attribute__((ext_vector_type(4)));

typedef __attribute__((address_space(1))) void gvoid_t;
typedef __attribute__((address_space(3))) void lvoid_t;

__device__ __forceinline__ void gload_lds16(const void* g, void* l) {
    __builtin_amdgcn_global_load_lds((gvoid_t*)const_cast<void*>(g),
                                     (lvoid_t*)l, 16, 0, 0);
}

// ---------- 64x64-tile GEMM: C[m,n] = sum_k A[m,k]*B[n,k], BK=32 ----------
// EPI 0: f16 out plain; EPI 1: f32 out plain
template<int EPI>
__global__ __launch_bounds__(256) void gemm64_nt(
    const f16* __restrict__ A, const f16* __restrict__ B, void* __restrict__ Cv,
    int M, int N, int K, long long sA, long long sB, long long sC)
{
    const int b = blockIdx.z;
    __shared__ alignas(16) f16 As[64 * 32];
    __shared__ alignas(16) f16 Bs[64 * 32];

    const int tid  = threadIdx.x;
    const int wave = tid >> 6;
    const int lane = tid & 63;
    const int quad = lane >> 4;
    const int l16  = lane & 15;

    const int m0 = blockIdx.x * 64;
    const int n0 = blockIdx.y * 64;
    const int wm = (wave >> 1) * 32;
    const int wn = (wave & 1) * 32;

    const f16* Ag = A + (long long)b * sA + (long long)(m0 + (tid >> 2)) * K + (tid & 3) * 8;
    const f16* Bg = B + (long long)b * sB + (long long)(n0 + (tid >> 2)) * K + (tid & 3) * 8;
    f16* Asl = &As[tid * 8];
    f16* Bsl = &Bs[tid * 8];

    f32x4 acc[2][2] = {};

    for (int kk = 0; kk < K; kk += 32) {
        gload_lds16(Ag, Asl);
        gload_lds16(Bg, Bsl);
        Ag += 32; Bg += 32;
        __syncthreads();

        f16x8 af[2], bf[2];
        #pragma unroll
        for (int i = 0; i < 2; i++)
            af[i] = *reinterpret_cast<const f16x8*>(&As[(wm + i * 16 + l16) * 32 + quad * 8]);
        #pragma unroll
        for (int j = 0; j < 2; j++)
            bf[j] = *reinterpret_cast<const f16x8*>(&Bs[(wn + j * 16 + l16) * 32 + quad * 8]);
        #pragma unroll
        for (int i = 0; i < 2; i++)
            #pragma unroll
            for (int j = 0; j < 2; j++)
                acc[i][j] = __builtin_amdgcn_mfma_f32_16x16x32_f16(af[i], bf[j], acc[i][j], 0, 0, 0);
        __syncthreads();
    }

    #pragma unroll
    for (int i = 0; i < 2; i++)
        #pragma unroll
        for (int j = 0; j < 2; j++)
            #pragma unroll
            for (int r = 0; r < 4; r++) {
                const int row = m0 + wm + i * 16 + quad * 4 + r;
                const int col = n0 + wn + j * 16 + l16;
                const long long idx = (long long)b * sC + (long long)row * N + col;
                if constexpr (EPI == 0) ((f16*)Cv)[idx] = (f16)acc[i][j][r];
                else                    ((float*)Cv)[idx] = acc[i][j][r];
            }
}

// ---------- 128x128-tile GEMM with per-(batch,row) f32 bias (final) ----------
__global__ __launch_bounds__(256) void gemm128_bias(
    const f16* __restrict__ A, const f16* __restrict__ B, float* __restrict__ C,
    const float* __restrict__ rowbias,
    int M, int N, int K, long long sA, long long sB, long long sC)
{
    const int b = blockIdx.z;
    __shared__ alignas(16) f16 As[128 * 32];
    __shared__ alignas(16) f16 Bs[128 * 32];

    const int tid  = threadIdx.x;
    const int wave = tid >> 6;
    const int lane = tid & 63;
    const int quad = lane >> 4;
    const int l16  = lane & 15;

    const int m0 = blockIdx.x * 128;
    const int n0 = blockIdx.y * 128;
    const int wm = (wave >> 1) * 64;
    const int wn = (wave & 1) * 64;

    const f16* Ag = A + (long long)b * sA + (long long)(m0 + (tid >> 2)) * K + (tid & 3) * 8;
    const f16* Bg = B + (long long)b * sB + (long long)(n0 + (tid >> 2)) * K + (tid & 3) * 8;
    f16* Asl = &As[tid * 8];
    f16* Bsl = &Bs[tid * 8];
    const long long rowskip = 64LL * K;

    f32x4 acc[4][4] = {};

    for (int kk = 0; kk < K; kk += 32) {
        gload_lds16(Ag,           Asl);
        gload_lds16(Ag + rowskip, Asl + 2048);
        gload_lds16(Bg,           Bsl);
        gload_lds16(Bg + rowskip, Bsl + 2048);
        Ag += 32; Bg += 32;
        __syncthreads();

        f16x8 af[4], bf[4];
        #pragma unroll
        for (int i = 0; i < 4; i++)
            af[i] = *reinterpret_cast<const f16x8*>(&As[(wm + i * 16 + l16) * 32 + quad * 8]);
        #pragma unroll
        for (int j = 0; j < 4; j++)
            bf[j] = *reinterpret_cast<const f16x8*>(&Bs[(wn + j * 16 + l16) * 32 + quad * 8]);
        #pragma unroll
        for (int i = 0; i < 4; i++)
            #pragma unroll
            for (int j = 0; j < 4; j++)
                acc[i][j] = __builtin_amdgcn_mfma_f32_16x16x32_f16(af[i], bf[j], acc[i][j], 0, 0, 0);
        __syncthreads();
    }

    #pragma unroll
    for (int i = 0; i < 4; i++)
        #pragma unroll
        for (int j = 0; j < 4; j++)
            #pragma unroll
            for (int r = 0; r < 4; r++) {
                const int row = m0 + wm + i * 16 + quad * 4 + r;
                const int col = n0 + wn + j * 16 + l16;
                const long long idx = (long long)b * sC + (long long)row * N + col;
                C[idx] = acc[i][j][r] + rowbias[(long long)b * M + row];
            }
}

// ---------- x [B,512,4096] f32 -> xh (cast) + xT (transpose-cast) + r (row sums)
__global__ __launch_bounds__(256) void transpose_cast_x(
    const float* __restrict__ x, f16* __restrict__ xh, f16* __restrict__ xT,
    float* __restrict__ r)
{
    __shared__ float t[64][65];
    const int b  = blockIdx.z;
    const int n0 = blockIdx.x * 64;
    const int c0 = blockIdx.y * 64;
    const int cg = threadIdx.x & 15;   // float4 group along n
    const int cr = threadIdx.x >> 4;   // 0..15

    const float* xb  = x  + ((long long)b * 512 + c0) * 4096 + n0;
    f16*         xhb = xh + ((long long)b * 512 + c0) * 4096 + n0;

    #pragma unroll
    for (int s = 0; s < 64; s += 16) {
        const int row = cr + s;
        const float4 ld = *reinterpret_cast<const float4*>(&xb[(long long)row * 4096 + cg * 4]);
        f16x4 h; h[0] = (f16)ld.x; h[1] = (f16)ld.y; h[2] = (f16)ld.z; h[3] = (f16)ld.w;
        *reinterpret_cast<f16x4*>(&xhb[(long long)row * 4096 + cg * 4]) = h;
        t[row][cg * 4 + 0] = ld.x; t[row][cg * 4 + 1] = ld.y;
        t[row][cg * 4 + 2] = ld.z; t[row][cg * 4 + 3] = ld.w;
        float sm = ld.x + ld.y + ld.z + ld.w;
        sm += __shfl_xor(sm, 1, 64); sm += __shfl_xor(sm, 2, 64);
        sm += __shfl_xor(sm, 4, 64); sm += __shfl_xor(sm, 8, 64);
        if (cg == 0) atomicAdd(&r[b * 512 + c0 + row], sm);
    }
    __syncthreads();
    f16* xTb = xT + ((long long)b * 4096 + n0) * 512 + c0;
    #pragma unroll
    for (int s = 0; s < 64; s += 16) {
        const int nr = cr + s;
        f16x4 h;
        h[0] = (f16)t[cg * 4 + 0][nr]; h[1] = (f16)t[cg * 4 + 1][nr];
        h[2] = (f16)t[cg * 4 + 2][nr]; h[3] = (f16)t[cg * 4 + 3][nr];
        *reinterpret_cast<f16x4*>(&xTb[(long long)nr * 512 + cg * 4]) = h;
    }
}

__global__ __launch_bounds__(256) void cast_w4(
    const float* __restrict__ W, f16* __restrict__ o)
{
    const int i = blockIdx.x * 256 + threadIdx.x;
    const float4 ld = reinterpret_cast<const float4*>(W)[i];
    f16x4 h; h[0] = (f16)ld.x; h[1] = (f16)ld.y; h[2] = (f16)ld.z; h[3] = (f16)ld.w;
    reinterpret_cast<f16x4*>(o)[i] = h;
}

// WT[e,d] = (f16) W[d,e]  (512x512)
__global__ __launch_bounds__(256) void transpose_cast_w(
    const float* __restrict__ W, f16* __restrict__ WT)
{
    __shared__ float t[32][33];
    const int r0 = blockIdx.y * 32, c0 = blockIdx.x * 32;
    const int tx = threadIdx.x & 31, ty = threadIdx.x >> 5;
    #pragma unroll
    for (int i = 0; i < 32; i += 8)
        t[ty + i][tx] = W[(long long)(r0 + ty + i) * 512 + c0 + tx];
    __syncthreads();
    #pragma unroll
    for (int i = 0; i < 32; i += 8)
        WT[(long long)(c0 + ty + i) * 512 + r0 + tx] = (f16)t[tx][ty + i];
}

// u1[b,i] = sum_c Wq[i,c] r[b,c]; u2[b,i] = sum_c Wk[i,c] r[b,c]
__global__ __launch_bounds__(256) void matvec_u(
    const float* __restrict__ Wq, const float* __restrict__ Wk,
    const float* __restrict__ r, float* __restrict__ u1, float* __restrict__ u2)
{
    const int w = blockIdx.x * 4 + (threadIdx.x >> 6);  // 0..16383
    const int lane = threadIdx.x & 63;
    const int which = w >> 13;
    const int b = (w >> 9) & 15;
    const int i = w & 511;
    const float* W = which ? Wk : Wq;
    const float* rb = r + b * 512;
    float s = 0.f;
    #pragma unroll
    for (int j = 0; j < 8; j++) {
        const int c = lane + 64 * j;
        s += W[(long long)i * 512 + c] * rb[c];
    }
    #pragma unroll
    for (int off = 32; off > 0; off >>= 1) s += __shfl_xor(s, off, 64);
    if (lane == 0) (which ? u2 : u1)[b * 512 + i] = s;
}

// softmax over rows of S with rank-1 bias terms; emits attn f16 + rowbias = attn.bv
__global__ __launch_bounds__(256) void softmax_bias(
    const float* __restrict__ S, const float* __restrict__ bq,
    const float* __restrict__ bk, const float* __restrict__ bv,
    const float* __restrict__ u1, const float* __restrict__ u2,
    f16* __restrict__ attn, float* __restrict__ rowbias)
{
    const int wave = threadIdx.x >> 6;
    const int lane = threadIdx.x & 63;
    const long long row = (long long)blockIdx.x * 4 + wave;  // b*512 + c
    const int b = (int)(row >> 9);
    const int c = (int)(row & 511);
    const float* src = S + row * 512;
    const float u1c = u1[row];
    const float bqc = bq[c];
    const float scale = 0.04419417382415922f;

    float v[8], bkv[8];
    float mx = -1e30f;
    #pragma unroll
    for (int j = 0; j < 8; j++) {
        const int d = lane + 64 * j;
        bkv[j] = bk[d];
        float val = src[d] + u1c * bkv[j] + bqc * u2[b * 512 + d] + 4096.0f * bqc * bkv[j];
        val *= scale;
        v[j] = val;
        mx = fmaxf(mx, val);
    }
    #pragma unroll
    for (int off = 32; off > 0; off >>= 1) mx = fmaxf(mx, __shfl_xor(mx, off, 64));
    float sum = 0.f;
    #pragma unroll
    for (int j = 0; j < 8; j++) { v[j] = __expf(v[j] - mx); sum += v[j]; }
    #pragma unroll
    for (int off = 32; off > 0; off >>= 1) sum += __shfl_xor(sum, off, 64);
    const float inv = 1.0f / sum;

    float rb_ = 0.f;
    f16* dst = attn + row * 512;
    #pragma unroll
    for (int j = 0; j < 8; j++) {
        const int d = lane + 64 * j;
        const float p = v[j] * inv;
        dst[d] = (f16)p;
        rb_ += p * bv[d];
    }
    #pragma unroll
    for (int off = 32; off > 0; off >>= 1) rb_ += __shfl_xor(rb_, off, 64);
    if (lane == 0) rowbias[row] = rb_;
}

extern "C" void kernel_launch(void* const* d_in, const int* in_sizes, int n_in,
                              void* d_out, int out_size, void* d_ws, size_t ws_size,
                              hipStream_t stream)
{
    const float* x  = (const float*)d_in[0];
    const float* Wq = (const float*)d_in[1];
    const float* bq = (const float*)d_in[2];
    const float* Wk = (const float*)d_in[3];
    const float* bk = (const float*)d_in[4];
    const float* Wv = (const float*)d_in[5];
    const float* bv = (const float*)d_in[6];
    float* out = (float*)d_out;

    const int B = 16, C = 512, N = 4096;
    const long long CN = (long long)C * N;   // 2097152
    const long long CC = (long long)C * C;   // 262144

    char* ws = (char*)d_ws;
    size_t off = 0;
    auto alloc = [&](size_t bytes) -> void* {
        void* p = ws + off;
        off += (bytes + 255) & ~(size_t)255;
        return p;
    };
    f16*   xh   = (f16*)  alloc((size_t)B * CN * 2);   // 64 MiB
    f16*   xT   = (f16*)  alloc((size_t)B * CN * 2);   // 64 MiB
    f16*   G    = (f16*)  alloc((size_t)B * CC * 2);   //  8 MiB
    f16*   T    = (f16*)  alloc((size_t)B * CC * 2);   //  8 MiB
    float* S    = (float*)alloc((size_t)B * CC * 4);   // 16 MiB
    f16*   attn = (f16*)  alloc((size_t)B * CC * 2);   //  8 MiB
    f16*   U    = (f16*)  alloc((size_t)B * CC * 2);   //  8 MiB
    f16*   Wqh  = (f16*)  alloc((size_t)CC * 2);
    f16*   Wkh  = (f16*)  alloc((size_t)CC * 2);
    f16*   WvT  = (f16*)  alloc((size_t)CC * 2);
    float* r    = (float*)alloc((size_t)B * C * 4);
    float* u1   = (float*)alloc((size_t)B * C * 4);
    float* u2   = (float*)alloc((size_t)B * C * 4);
    float* rwb  = (float*)alloc((size_t)B * C * 4);
    (void)ws_size;

    hipMemsetAsync(r, 0, (size_t)B * C * 4, stream);

    transpose_cast_x<<<dim3(N / 64, C / 64, B), 256, 0, stream>>>(x, xh, xT, r);
    cast_w4<<<dim3(C * C / 1024), 256, 0, stream>>>(Wq, Wqh);
    cast_w4<<<dim3(C * C / 1024), 256, 0, stream>>>(Wk, Wkh);
    transpose_cast_w<<<dim3(16, 16), 256, 0, stream>>>(Wv, WvT);
    matvec_u<<<dim3(2 * B * C / 4), 256, 0, stream>>>(Wq, Wk, r, u1, u2);

    // G[b] = xh[b] xh[b]^T   [512,512] f16, K=4096
    gemm64_nt<0><<<dim3(8, 8, B), 256, 0, stream>>>(xh, xh, G, C, C, N, CN, CN, CC);
    // T[b] = Wq G[b]  (uses G symmetry)  f16, K=512
    gemm64_nt<0><<<dim3(8, 8, B), 256, 0, stream>>>(Wqh, G, T, C, C, C, 0LL, CC, CC);
    // Sraw[b] = T[b] Wk^T  f32
    gemm64_nt<1><<<dim3(8, 8, B), 256, 0, stream>>>(T, Wkh, S, C, C, C, CC, 0LL, CC);
    // attn = softmax((Sraw + rank1)*scale), rowbias = attn . bv
    softmax_bias<<<dim3(B * C / 4), 256, 0, stream>>>(S, bq, bk, bv, u1, u2, attn, rwb);
    // U[b] = attn[b] Wv  f16
    gemm64_nt<0><<<dim3(8, 8, B), 256, 0, stream>>>(attn, WvT, U, C, C, C, CC, 0LL, CC);
    // out[b] = U[b] x[b] + rowbias  f32  (B operand = xT, K=512)
    gemm128_bias<<<dim3(C / 128, N / 128, B), 256, 0, stream>>>(
        U, xT, out, rwb, C, N, C, CC, CN, CN);
}

// Round 3
// 452.176 us; speedup vs baseline: 1.3272x; 1.0675x over previous
//
#include <hip/hip_runtime.h>
#include <cstdint>

typedef _Float16 f16;
typedef f16 f16x4 __attribute__((ext_vector_type(4)));
typedef f16 f16x8 __attribute__((ext_vector_type(8)));
typedef float f32x4 __attribute__((ext_vector_type(4)));

typedef __attribute__((address_space(1))) void gvoid_t;
typedef __attribute__((address_space(3))) void lvoid_t;

__device__ __forceinline__ void gload_lds16(const void* g, void* l) {
    __builtin_amdgcn_global_load_lds((gvoid_t*)const_cast<void*>(g),
                                     (lvoid_t*)l, 16, 0, 0);
}

// ---------- 64x64-tile GEMM: C[m,n] = sum_k A[m,k]*B[n,k], BK=32 ----------
template<int EPI>
__global__ __launch_bounds__(256) void gemm64_nt(
    const f16* __restrict__ A, const f16* __restrict__ B, void* __restrict__ Cv,
    int M, int N, int K, long long sA, long long sB, long long sC)
{
    const int b = blockIdx.z;
    __shared__ alignas(16) f16 As[64 * 32];
    __shared__ alignas(16) f16 Bs[64 * 32];

    const int tid  = threadIdx.x;
    const int wave = tid >> 6;
    const int lane = tid & 63;
    const int quad = lane >> 4;
    const int l16  = lane & 15;

    const int m0 = blockIdx.x * 64;
    const int n0 = blockIdx.y * 64;
    const int wm = (wave >> 1) * 32;
    const int wn = (wave & 1) * 32;

    const f16* Ag = A + (long long)b * sA + (long long)(m0 + (tid >> 2)) * K + (tid & 3) * 8;
    const f16* Bg = B + (long long)b * sB + (long long)(n0 + (tid >> 2)) * K + (tid & 3) * 8;
    f16* Asl = &As[tid * 8];
    f16* Bsl = &Bs[tid * 8];

    f32x4 acc[2][2] = {};

    for (int kk = 0; kk < K; kk += 32) {
        gload_lds16(Ag, Asl);
        gload_lds16(Bg, Bsl);
        Ag += 32; Bg += 32;
        __syncthreads();

        f16x8 af[2], bf[2];
        #pragma unroll
        for (int i = 0; i < 2; i++)
            af[i] = *reinterpret_cast<const f16x8*>(&As[(wm + i * 16 + l16) * 32 + quad * 8]);
        #pragma unroll
        for (int j = 0; j < 2; j++)
            bf[j] = *reinterpret_cast<const f16x8*>(&Bs[(wn + j * 16 + l16) * 32 + quad * 8]);
        #pragma unroll
        for (int i = 0; i < 2; i++)
            #pragma unroll
            for (int j = 0; j < 2; j++)
                acc[i][j] = __builtin_amdgcn_mfma_f32_16x16x32_f16(af[i], bf[j], acc[i][j], 0, 0, 0);
        __syncthreads();
    }

    #pragma unroll
    for (int i = 0; i < 2; i++)
        #pragma unroll
        for (int j = 0; j < 2; j++)
            #pragma unroll
            for (int r = 0; r < 4; r++) {
                const int row = m0 + wm + i * 16 + quad * 4 + r;
                const int col = n0 + wn + j * 16 + l16;
                const long long idx = (long long)b * sC + (long long)row * N + col;
                if constexpr (EPI == 0) ((f16*)Cv)[idx] = (f16)acc[i][j][r];
                else                    ((float*)Cv)[idx] = acc[i][j][r];
            }
}

// ---------- Gram split-K: P[slice][b] = xh[b][:,slice] * xh[b][:,slice]^T
// 128x128 tile, BK=32, K-slice=1024. grid (4,4,B*4); z = b*4 + slice.
__global__ __launch_bounds__(256) void gram_splitk(
    const f16* __restrict__ xh, float* __restrict__ P)
{
    const int b     = blockIdx.z >> 2;
    const int slice = blockIdx.z & 3;

    __shared__ alignas(16) f16 As[128 * 32];
    __shared__ alignas(16) f16 Bs[128 * 32];

    const int tid  = threadIdx.x;
    const int wave = tid >> 6;
    const int lane = tid & 63;
    const int quad = lane >> 4;
    const int l16  = lane & 15;

    const int m0 = blockIdx.x * 128;
    const int n0 = blockIdx.y * 128;
    const int wm = (wave >> 1) * 64;
    const int wn = (wave & 1) * 64;

    const f16* base = xh + (long long)b * (512LL * 4096) + slice * 1024;
    const f16* Ag = base + (long long)(m0 + (tid >> 2)) * 4096 + (tid & 3) * 8;
    const f16* Bg = base + (long long)(n0 + (tid >> 2)) * 4096 + (tid & 3) * 8;
    f16* Asl = &As[tid * 8];
    f16* Bsl = &Bs[tid * 8];
    const long long rowskip = 64LL * 4096;

    f32x4 acc[4][4] = {};

    for (int kk = 0; kk < 1024; kk += 32) {
        gload_lds16(Ag,           Asl);
        gload_lds16(Ag + rowskip, Asl + 2048);
        gload_lds16(Bg,           Bsl);
        gload_lds16(Bg + rowskip, Bsl + 2048);
        Ag += 32; Bg += 32;
        __syncthreads();

        f16x8 af[4], bf[4];
        #pragma unroll
        for (int i = 0; i < 4; i++)
            af[i] = *reinterpret_cast<const f16x8*>(&As[(wm + i * 16 + l16) * 32 + quad * 8]);
        #pragma unroll
        for (int j = 0; j < 4; j++)
            bf[j] = *reinterpret_cast<const f16x8*>(&Bs[(wn + j * 16 + l16) * 32 + quad * 8]);
        #pragma unroll
        for (int i = 0; i < 4; i++)
            #pragma unroll
            for (int j = 0; j < 4; j++)
                acc[i][j] = __builtin_amdgcn_mfma_f32_16x16x32_f16(af[i], bf[j], acc[i][j], 0, 0, 0);
        __syncthreads();
    }

    float* Pt = P + ((long long)slice * 16 + b) * (512LL * 512);
    #pragma unroll
    for (int i = 0; i < 4; i++)
        #pragma unroll
        for (int j = 0; j < 4; j++)
            #pragma unroll
            for (int r = 0; r < 4; r++) {
                const int row = m0 + wm + i * 16 + quad * 4 + r;
                const int col = n0 + wn + j * 16 + l16;
                Pt[(long long)row * 512 + col] = acc[i][j][r];
            }
}

// G16 = (f16) sum_{s<4} P[s]
__global__ __launch_bounds__(256) void reduce_cast(
    const float* __restrict__ P, f16* __restrict__ G16)
{
    const long long i4 = (long long)blockIdx.x * 256 + threadIdx.x;
    const long long stride4 = 16LL * 512 * 512 / 4;
    const float4 a = reinterpret_cast<const float4*>(P)[i4];
    const float4 b = reinterpret_cast<const float4*>(P)[i4 + stride4];
    const float4 c = reinterpret_cast<const float4*>(P)[i4 + 2 * stride4];
    const float4 d = reinterpret_cast<const float4*>(P)[i4 + 3 * stride4];
    f16x4 h;
    h[0] = (f16)(a.x + b.x + c.x + d.x);
    h[1] = (f16)(a.y + b.y + c.y + d.y);
    h[2] = (f16)(a.z + b.z + c.z + d.z);
    h[3] = (f16)(a.w + b.w + c.w + d.w);
    reinterpret_cast<f16x4*>(G16)[i4] = h;
}

// ---------- 128x128-tile GEMM with per-(batch,row) f32 bias (final) ----------
__global__ __launch_bounds__(256) void gemm128_bias(
    const f16* __restrict__ A, const f16* __restrict__ B, float* __restrict__ C,
    const float* __restrict__ rowbias,
    int M, int N, int K, long long sA, long long sB, long long sC)
{
    const int b = blockIdx.z;
    __shared__ alignas(16) f16 As[128 * 32];
    __shared__ alignas(16) f16 Bs[128 * 32];

    const int tid  = threadIdx.x;
    const int wave = tid >> 6;
    const int lane = tid & 63;
    const int quad = lane >> 4;
    const int l16  = lane & 15;

    const int m0 = blockIdx.x * 128;
    const int n0 = blockIdx.y * 128;
    const int wm = (wave >> 1) * 64;
    const int wn = (wave & 1) * 64;

    const f16* Ag = A + (long long)b * sA + (long long)(m0 + (tid >> 2)) * K + (tid & 3) * 8;
    const f16* Bg = B + (long long)b * sB + (long long)(n0 + (tid >> 2)) * K + (tid & 3) * 8;
    f16* Asl = &As[tid * 8];
    f16* Bsl = &Bs[tid * 8];
    const long long rowskip = 64LL * K;

    f32x4 acc[4][4] = {};

    for (int kk = 0; kk < K; kk += 32) {
        gload_lds16(Ag,           Asl);
        gload_lds16(Ag + rowskip, Asl + 2048);
        gload_lds16(Bg,           Bsl);
        gload_lds16(Bg + rowskip, Bsl + 2048);
        Ag += 32; Bg += 32;
        __syncthreads();

        f16x8 af[4], bf[4];
        #pragma unroll
        for (int i = 0; i < 4; i++)
            af[i] = *reinterpret_cast<const f16x8*>(&As[(wm + i * 16 + l16) * 32 + quad * 8]);
        #pragma unroll
        for (int j = 0; j < 4; j++)
            bf[j] = *reinterpret_cast<const f16x8*>(&Bs[(wn + j * 16 + l16) * 32 + quad * 8]);
        #pragma unroll
        for (int i = 0; i < 4; i++)
            #pragma unroll
            for (int j = 0; j < 4; j++)
                acc[i][j] = __builtin_amdgcn_mfma_f32_16x16x32_f16(af[i], bf[j], acc[i][j], 0, 0, 0);
        __syncthreads();
    }

    #pragma unroll
    for (int i = 0; i < 4; i++)
        #pragma unroll
        for (int j = 0; j < 4; j++)
            #pragma unroll
            for (int r = 0; r < 4; r++) {
                const int row = m0 + wm + i * 16 + quad * 4 + r;
                const int col = n0 + wn + j * 16 + l16;
                const long long idx = (long long)b * sC + (long long)row * N + col;
                C[idx] = acc[i][j][r] + rowbias[(long long)b * M + row];
            }
}

// ---------- x [B,512,4096] f32 -> xh (cast) + xT (transpose-cast) + r (row sums)
__global__ __launch_bounds__(256) void transpose_cast_x(
    const float* __restrict__ x, f16* __restrict__ xh, f16* __restrict__ xT,
    float* __restrict__ r)
{
    __shared__ float t[64][65];
    const int b  = blockIdx.z;
    const int n0 = blockIdx.x * 64;
    const int c0 = blockIdx.y * 64;
    const int cg = threadIdx.x & 15;
    const int cr = threadIdx.x >> 4;

    const float* xb  = x  + ((long long)b * 512 + c0) * 4096 + n0;
    f16*         xhb = xh + ((long long)b * 512 + c0) * 4096 + n0;

    #pragma unroll
    for (int s = 0; s < 64; s += 16) {
        const int row = cr + s;
        const float4 ld = *reinterpret_cast<const float4*>(&xb[(long long)row * 4096 + cg * 4]);
        f16x4 h; h[0] = (f16)ld.x; h[1] = (f16)ld.y; h[2] = (f16)ld.z; h[3] = (f16)ld.w;
        *reinterpret_cast<f16x4*>(&xhb[(long long)row * 4096 + cg * 4]) = h;
        t[row][cg * 4 + 0] = ld.x; t[row][cg * 4 + 1] = ld.y;
        t[row][cg * 4 + 2] = ld.z; t[row][cg * 4 + 3] = ld.w;
        float sm = ld.x + ld.y + ld.z + ld.w;
        sm += __shfl_xor(sm, 1, 64); sm += __shfl_xor(sm, 2, 64);
        sm += __shfl_xor(sm, 4, 64); sm += __shfl_xor(sm, 8, 64);
        if (cg == 0) atomicAdd(&r[b * 512 + c0 + row], sm);
    }
    __syncthreads();
    f16* xTb = xT + ((long long)b * 4096 + n0) * 512 + c0;
    #pragma unroll
    for (int s = 0; s < 64; s += 16) {
        const int nr = cr + s;
        f16x4 h;
        h[0] = (f16)t[cg * 4 + 0][nr]; h[1] = (f16)t[cg * 4 + 1][nr];
        h[2] = (f16)t[cg * 4 + 2][nr]; h[3] = (f16)t[cg * 4 + 3][nr];
        *reinterpret_cast<f16x4*>(&xTb[(long long)nr * 512 + cg * 4]) = h;
    }
}

__global__ __launch_bounds__(256) void cast_w2(
    const float* __restrict__ Wq, const float* __restrict__ Wk,
    f16* __restrict__ oq, f16* __restrict__ ok)
{
    const int blk = blockIdx.x;
    const float* W = (blk < 256) ? Wq : Wk;
    f16* o = (blk < 256) ? oq : ok;
    const int i = (blk & 255) * 256 + threadIdx.x;
    const float4 ld = reinterpret_cast<const float4*>(W)[i];
    f16x4 h; h[0] = (f16)ld.x; h[1] = (f16)ld.y; h[2] = (f16)ld.z; h[3] = (f16)ld.w;
    reinterpret_cast<f16x4*>(o)[i] = h;
}

// WT[e,d] = (f16) W[d,e]  (512x512)
__global__ __launch_bounds__(256) void transpose_cast_w(
    const float* __restrict__ W, f16* __restrict__ WT)
{
    __shared__ float t[32][33];
    const int r0 = blockIdx.y * 32, c0 = blockIdx.x * 32;
    const int tx = threadIdx.x & 31, ty = threadIdx.x >> 5;
    #pragma unroll
    for (int i = 0; i < 32; i += 8)
        t[ty + i][tx] = W[(long long)(r0 + ty + i) * 512 + c0 + tx];
    __syncthreads();
    #pragma unroll
    for (int i = 0; i < 32; i += 8)
        WT[(long long)(c0 + ty + i) * 512 + r0 + tx] = (f16)t[tx][ty + i];
}

// u1[b,i] = sum_c Wq[i,c] r[b,c]; u2[b,i] = sum_c Wk[i,c] r[b,c]
__global__ __launch_bounds__(256) void matvec_u(
    const float* __restrict__ Wq, const float* __restrict__ Wk,
    const float* __restrict__ r, float* __restrict__ u1, float* __restrict__ u2)
{
    const int w = blockIdx.x * 4 + (threadIdx.x >> 6);
    const int lane = threadIdx.x & 63;
    const int which = w >> 13;
    const int b = (w >> 9) & 15;
    const int i = w & 511;
    const float* W = which ? Wk : Wq;
    const float* rb = r + b * 512;
    float s = 0.f;
    #pragma unroll
    for (int j = 0; j < 8; j++) {
        const int c = lane + 64 * j;
        s += W[(long long)i * 512 + c] * rb[c];
    }
    #pragma unroll
    for (int off = 32; off > 0; off >>= 1) s += __shfl_xor(s, off, 64);
    if (lane == 0) (which ? u2 : u1)[b * 512 + i] = s;
}

// softmax over rows of S with rank-1 bias terms; emits attn f16 + rowbias = attn.bv
__global__ __launch_bounds__(256) void softmax_bias(
    const float* __restrict__ S, const float* __restrict__ bq,
    const float* __restrict__ bk, const float* __restrict__ bv,
    const float* __restrict__ u1, const float* __restrict__ u2,
    f16* __restrict__ attn, float* __restrict__ rowbias)
{
    const int wave = threadIdx.x >> 6;
    const int lane = threadIdx.x & 63;
    const long long row = (long long)blockIdx.x * 4 + wave;
    const int b = (int)(row >> 9);
    const int c = (int)(row & 511);
    const float* src = S + row * 512;
    const float u1c = u1[row];
    const float bqc = bq[c];
    const float scale = 0.04419417382415922f;

    float v[8], bkv[8];
    float mx = -1e30f;
    #pragma unroll
    for (int j = 0; j < 8; j++) {
        const int d = lane + 64 * j;
        bkv[j] = bk[d];
        float val = src[d] + u1c * bkv[j] + bqc * u2[b * 512 + d] + 4096.0f * bqc * bkv[j];
        val *= scale;
        v[j] = val;
        mx = fmaxf(mx, val);
    }
    #pragma unroll
    for (int off = 32; off > 0; off >>= 1) mx = fmaxf(mx, __shfl_xor(mx, off, 64));
    float sum = 0.f;
    #pragma unroll
    for (int j = 0; j < 8; j++) { v[j] = __expf(v[j] - mx); sum += v[j]; }
    #pragma unroll
    for (int off = 32; off > 0; off >>= 1) sum += __shfl_xor(sum, off, 64);
    const float inv = 1.0f / sum;

    float rb_ = 0.f;
    f16* dst = attn + row * 512;
    #pragma unroll
    for (int j = 0; j < 8; j++) {
        const int d = lane + 64 * j;
        const float p = v[j] * inv;
        dst[d] = (f16)p;
        rb_ += p * bv[d];
    }
    #pragma unroll
    for (int off = 32; off > 0; off >>= 1) rb_ += __shfl_xor(rb_, off, 64);
    if (lane == 0) rowbias[row] = rb_;
}

extern "C" void kernel_launch(void* const* d_in, const int* in_sizes, int n_in,
                              void* d_out, int out_size, void* d_ws, size_t ws_size,
                              hipStream_t stream)
{
    const float* x  = (const float*)d_in[0];
    const float* Wq = (const float*)d_in[1];
    const float* bq = (const float*)d_in[2];
    const float* Wk = (const float*)d_in[3];
    const float* bk = (const float*)d_in[4];
    const float* Wv = (const float*)d_in[5];
    const float* bv = (const float*)d_in[6];
    float* out = (float*)d_out;

    const int B = 16, C = 512, N = 4096;
    const long long CN = (long long)C * N;
    const long long CC = (long long)C * C;

    char* ws = (char*)d_ws;
    size_t off = 0;
    auto alloc = [&](size_t bytes) -> void* {
        void* p = ws + off;
        off += (bytes + 255) & ~(size_t)255;
        return p;
    };
    f16*   xh   = (f16*)  alloc((size_t)B * CN * 2);
    f16*   xT   = (f16*)  alloc((size_t)B * CN * 2);
    float* Gp   = (float*)alloc((size_t)4 * B * CC * 4);
    f16*   G    = (f16*)  alloc((size_t)B * CC * 2);
    f16*   T    = (f16*)  alloc((size_t)B * CC * 2);
    float* S    = (float*)alloc((size_t)B * CC * 4);
    f16*   attn = (f16*)  alloc((size_t)B * CC * 2);
    f16*   U    = (f16*)  alloc((size_t)B * CC * 2);
    f16*   Wqh  = (f16*)  alloc((size_t)CC * 2);
    f16*   Wkh  = (f16*)  alloc((size_t)CC * 2);
    f16*   WvT  = (f16*)  alloc((size_t)CC * 2);
    float* r    = (float*)alloc((size_t)B * C * 4);
    float* u1   = (float*)alloc((size_t)B * C * 4);
    float* u2   = (float*)alloc((size_t)B * C * 4);
    float* rwb  = (float*)alloc((size_t)B * C * 4);
    (void)ws_size;

    hipMemsetAsync(r, 0, (size_t)B * C * 4, stream);

    transpose_cast_x<<<dim3(N / 64, C / 64, B), 256, 0, stream>>>(x, xh, xT, r);
    cast_w2<<<dim3(512), 256, 0, stream>>>(Wq, Wk, Wqh, Wkh);
    transpose_cast_w<<<dim3(16, 16), 256, 0, stream>>>(Wv, WvT);
    matvec_u<<<dim3(2 * B * C / 4), 256, 0, stream>>>(Wq, Wk, r, u1, u2);

    gram_splitk<<<dim3(4, 4, B * 4), 256, 0, stream>>>(xh, Gp);
    reduce_cast<<<dim3((unsigned)(B * CC / 4 / 256)), 256, 0, stream>>>(Gp, G);

    gemm64_nt<0><<<dim3(8, 8, B), 256, 0, stream>>>(Wqh, G, T, C, C, C, 0LL, CC, CC);
    gemm64_nt<1><<<dim3(8, 8, B), 256, 0, stream>>>(T, Wkh, S, C, C, C, CC, 0LL, CC);
    softmax_bias<<<dim3(B * C / 4), 256, 0, stream>>>(S, bq, bk, bv, u1, u2, attn, rwb);
    gemm64_nt<0><<<dim3(8, 8, B), 256, 0, stream>>>(attn, WvT, U, C, C, C, CC, 0LL, CC);
    gemm128_bias<<<dim3(C / 128, N / 128, B), 256, 0, stream>>>(
        U, xT, out, rwb, C, N, C, CC, CN, CN);
}